// Round 1
// baseline (322.253 us; speedup 1.0000x reference)
//
#include <hip/hip_runtime.h>
#include <stdint.h>

// Problem constants
#define NB 8
#define NC 256
#define NO 768
#define NN 16384
#define KSPL 8
#define KCHUNK 2048  // NN / KSPL

typedef short bf16x8 __attribute__((ext_vector_type(8)));  // 8 bf16 = 4 VGPR
typedef float f32x4  __attribute__((ext_vector_type(4)));
typedef uint32_t u32;

__device__ __forceinline__ unsigned short f2bf(float f) {
  union { float f; unsigned u; } c; c.f = f;
  return (unsigned short)((c.u + 0x7FFFu + ((c.u >> 16) & 1u)) >> 16);  // RNE
}
__device__ __forceinline__ float bf2f(unsigned short h) {
  union { unsigned u; float f; } c; c.u = ((unsigned)h) << 16;
  return c.f;
}

// async global->LDS, 16B per lane; LDS dest is wave-uniform base + lane*16
__device__ __forceinline__ void gload16(const void* g, void* l) {
  __builtin_amdgcn_global_load_lds(
      (const __attribute__((address_space(1))) u32*)g,
      (__attribute__((address_space(3))) u32*)l, 16, 0, 0);
}

// Stage a [128 rows x 64 bf16] tile (row stride ld_bytes) into 16KB of LDS.
// T2 XOR-swizzle: physical 16B slot p of row holds logical slot p ^ (row&7);
// applied on the (per-lane) global source, LDS stays linear (guide rule #21).
__device__ __forceinline__ void stage_tile(const char* src, int ld_bytes,
                                           char* lds, int w, int l) {
#pragma unroll
  for (int i = 0; i < 4; ++i) {
    int s = (w * 4 + i) * 64 + l;      // 0..1023 : 16B chunk index
    int row = s >> 3;
    int srcslot = (l & 7) ^ (row & 7);
    gload16(src + (size_t)row * ld_bytes + srcslot * 16,
            lds + (w * 4 + i) * 1024);
  }
}

// m97-style TN GEMM core: C[128,128] += A[128,K] * B[128,K]^T, K = ktiles*64.
// 256 threads = 4 waves as 2x2, each wave 64x64 via 4x4 frags of 16x16x32 bf16.
__device__ __forceinline__ void gemm_core(const char* A, int lda_b,
                                          const char* Bm, int ldb_b, int ktiles,
                                          char* smem, int tid, f32x4 acc[4][4]) {
  const int w = tid >> 6, l = tid & 63;
  const int wm = w >> 1, wn = w & 1;
  char* As = smem;
  char* Bs = smem + 16384;
  for (int kt = 0; kt < ktiles; ++kt) {
    stage_tile(A + kt * 128, lda_b, As, w, l);
    stage_tile(Bm + kt * 128, ldb_b, Bs, w, l);
    __syncthreads();  // compiler drains vmcnt before s_barrier
#pragma unroll
    for (int ks = 0; ks < 2; ++ks) {
      bf16x8 av[4], bv[4];
      const int kb = ks * 64 + ((l >> 4) << 4);  // byte offset of lane's 8 bf16
#pragma unroll
      for (int m = 0; m < 4; ++m) {
        int row = wm * 64 + m * 16 + (l & 15);
        av[m] = *(const bf16x8*)(As + row * 128 + (kb ^ ((row & 7) << 4)));
      }
#pragma unroll
      for (int nq = 0; nq < 4; ++nq) {
        int row = wn * 64 + nq * 16 + (l & 15);
        bv[nq] = *(const bf16x8*)(Bs + row * 128 + (kb ^ ((row & 7) << 4)));
      }
#pragma unroll
      for (int m = 0; m < 4; ++m)
#pragma unroll
        for (int nq = 0; nq < 4; ++nq)
          acc[m][nq] = __builtin_amdgcn_mfma_f32_16x16x32_bf16(
              av[m], bv[nq], acc[m][nq], 0, 0, 0);
    }
    __syncthreads();
  }
}

// ---- Wdw[o][c] = w_qkv[o][c] * w_dw[o], bf16 -------------------------------
__global__ __launch_bounds__(256) void k_prepw(const float* __restrict__ wqkv,
                                               const float* __restrict__ wdw,
                                               char* __restrict__ out) {
  int o = blockIdx.x, c = threadIdx.x;
  ((unsigned short*)out)[o * NC + c] = f2bf(wqkv[o * NC + c] * wdw[o]);
}

// ---- xT[b][n][c] = bf16(x[b][c][n]) ----------------------------------------
__global__ __launch_bounds__(256) void k_transpose(const float* __restrict__ x,
                                                   char* __restrict__ xt) {
  __shared__ float t[64][68];  // +4 pad
  const int tid = threadIdx.x;
  const int ntile = blockIdx.x, ctile = blockIdx.y, b = blockIdx.z;
  {
    int r = tid >> 2, q = (tid & 3) * 16;
    const float* src = x + ((size_t)(b * NC + ctile * 64 + r)) * NN + ntile * 64 + q;
#pragma unroll
    for (int i = 0; i < 4; ++i) {
      float4 v = *(const float4*)(src + i * 4);
      *(float4*)&t[r][q + i * 4] = v;
    }
  }
  __syncthreads();
  {
    int nl = tid >> 2, cq = (tid & 3) * 16;
    unsigned short outv[16] __attribute__((aligned(16)));
#pragma unroll
    for (int i = 0; i < 16; ++i) outv[i] = f2bf(t[cq + i][nl]);
    char* dst = xt + (((size_t)b * NN + ntile * 64 + nl) * NC + ctile * 64 + cq) * 2;
    *(uint4*)(dst) = *(const uint4*)(outv);
    *(uint4*)(dst + 16) = *(const uint4*)(outv + 8);
  }
}

// ---- GEMM1: qkv = Wdw @ x ; q,k -> qk[b][0..511][n] ; v -> vT[b][n][c] -----
__global__ __launch_bounds__(256) void k_gemm1(const char* __restrict__ wdw,
                                               const char* __restrict__ xt,
                                               char* __restrict__ qk,
                                               char* __restrict__ vt) {
  __shared__ char smem[32768];
  const int tid = threadIdx.x;
  const int nt = blockIdx.x, mt = blockIdx.y, b = blockIdx.z;
  f32x4 acc[4][4];
#pragma unroll
  for (int m = 0; m < 4; ++m)
#pragma unroll
    for (int nq = 0; nq < 4; ++nq) acc[m][nq] = (f32x4){0.f, 0.f, 0.f, 0.f};
  const char* Ap = wdw + (size_t)mt * 128 * 512;
  const char* Bp = xt + ((size_t)b * NN + (size_t)nt * 128) * 512;
  gemm_core(Ap, 512, Bp, 512, 4, smem, tid, acc);

  const int w = tid >> 6, l = tid & 63;
  const int wm = w >> 1, wn = w & 1;
  if (mt < 4) {
    // q,k: bounce bf16 [128 o][128 n] (swizzled), then 16B coalesced stores
#pragma unroll
    for (int m = 0; m < 4; ++m)
#pragma unroll
      for (int nq = 0; nq < 4; ++nq)
#pragma unroll
        for (int r = 0; r < 4; ++r) {
          int orow = wm * 64 + m * 16 + ((l >> 4) << 2) + r;
          int ncol = wn * 64 + nq * 16 + (l & 15);
          *(unsigned short*)(smem + orow * 256 + ((ncol * 2) ^ ((orow & 7) << 4))) =
              f2bf(acc[m][nq][r]);
        }
    __syncthreads();
    const int rrow = tid >> 1, half = tid & 1;
    char* dst = qk + (((size_t)(b * 512 + mt * 128 + rrow)) * NN + (size_t)nt * 128) * 2;
#pragma unroll
    for (int j = 0; j < 8; ++j) {
      int lb = half * 128 + j * 16;
      *(uint4*)(dst + lb) =
          *(const uint4*)(smem + rrow * 256 + (lb ^ ((rrow & 7) << 4)));
    }
  } else {
    // v: bounce TRANSPOSED [128 n][128 o], then coalesced stores into vT[b][n][c]
#pragma unroll
    for (int m = 0; m < 4; ++m)
#pragma unroll
      for (int nq = 0; nq < 4; ++nq)
#pragma unroll
        for (int r = 0; r < 4; ++r) {
          int orow = wm * 64 + m * 16 + ((l >> 4) << 2) + r;
          int ncol = wn * 64 + nq * 16 + (l & 15);
          *(unsigned short*)(smem + ncol * 256 + ((orow * 2) ^ ((ncol & 7) << 4))) =
              f2bf(acc[m][nq][r]);
        }
    __syncthreads();
    const int nrow = tid >> 1, half = tid & 1;
    char* dst = vt + (((size_t)b * NN + nt * 128 + nrow) * 256 + (size_t)(mt - 4) * 128) * 2;
#pragma unroll
    for (int j = 0; j < 8; ++j) {
      int lb = half * 128 + j * 16;
      *(uint4*)(dst + lb) =
          *(const uint4*)(smem + nrow * 256 + (lb ^ ((nrow & 7) << 4)));
    }
  }
}

// ---- row L2 norms of q,k: inv[b*512+oc] = 1/max(||row||, 1e-12) ------------
__global__ __launch_bounds__(256) void k_norm(const char* __restrict__ qk,
                                              float* __restrict__ inv) {
  const int w = threadIdx.x >> 6, l = threadIdx.x & 63;
  const int row = blockIdx.x * 4 + w;  // 0..4095
  const uint4* p = (const uint4*)(qk + (size_t)row * NN * 2);
  float s = 0.f;
  for (int i = 0; i < 32; ++i) {
    uint4 v = p[i * 64 + l];
    unsigned a[4] = {v.x, v.y, v.z, v.w};
#pragma unroll
    for (int j = 0; j < 4; ++j) {
      float lo = bf2f((unsigned short)(a[j] & 0xffff));
      float hi = bf2f((unsigned short)(a[j] >> 16));
      s += lo * lo + hi * hi;
    }
  }
#pragma unroll
  for (int off = 32; off; off >>= 1) s += __shfl_xor(s, off);
  if (l == 0) inv[row] = 1.0f / fmaxf(sqrtf(s), 1e-12f);
}

// ---- GEMM2 (split-K): Spart[ks][b][c][d] = q_chunk @ k_chunk^T -------------
__global__ __launch_bounds__(256) void k_gemm2(const char* __restrict__ qk,
                                               float* __restrict__ spart) {
  __shared__ char smem[32768];
  const int tid = threadIdx.x;
  const int mt = blockIdx.x & 1, dt = blockIdx.x >> 1;
  const int ks = blockIdx.y, b = blockIdx.z;
  f32x4 acc[4][4];
#pragma unroll
  for (int m = 0; m < 4; ++m)
#pragma unroll
    for (int nq = 0; nq < 4; ++nq) acc[m][nq] = (f32x4){0.f, 0.f, 0.f, 0.f};
  const char* Ap = qk + ((size_t)(b * 512 + mt * 128) * NN + (size_t)ks * KCHUNK) * 2;
  const char* Bp = qk + ((size_t)(b * 512 + 256 + dt * 128) * NN + (size_t)ks * KCHUNK) * 2;
  gemm_core(Ap, NN * 2, Bp, NN * 2, KCHUNK / 64, smem, tid, acc);
  const int w = tid >> 6, l = tid & 63, wm = w >> 1, wn = w & 1;
#pragma unroll
  for (int m = 0; m < 4; ++m)
#pragma unroll
    for (int nq = 0; nq < 4; ++nq)
#pragma unroll
      for (int r = 0; r < 4; ++r) {
        int c = mt * 128 + wm * 64 + m * 16 + ((l >> 4) << 2) + r;
        int d = dt * 128 + wn * 64 + nq * 16 + (l & 15);
        spart[(((size_t)ks * NB + b) * 256 + c) * 256 + d] = acc[m][nq][r];
      }
}

// ---- softmax over d: attn[b][c][d] -----------------------------------------
__global__ __launch_bounds__(256) void k_softmax(const float* __restrict__ spart,
                                                 const float* __restrict__ inv,
                                                 const float* __restrict__ temp,
                                                 float* __restrict__ attn) {
  const int d = threadIdx.x, c = blockIdx.x, b = blockIdx.y;
  float s = 0.f;
#pragma unroll
  for (int ks = 0; ks < KSPL; ++ks)
    s += spart[(((size_t)ks * NB + b) * 256 + c) * 256 + d];
  float logit = s * inv[b * 512 + c] * inv[b * 512 + 256 + d] * temp[0];
  float m = logit;
#pragma unroll
  for (int off = 32; off; off >>= 1) m = fmaxf(m, __shfl_xor(m, off));
  __shared__ float red[4];
  __shared__ float red2[4];
  const int w = d >> 6, l = d & 63;
  if (l == 0) red[w] = m;
  __syncthreads();
  m = fmaxf(fmaxf(red[0], red[1]), fmaxf(red[2], red[3]));
  float e = __expf(logit - m);
  float t2 = e;
#pragma unroll
  for (int off = 32; off; off >>= 1) t2 += __shfl_xor(t2, off);
  if (l == 0) red2[w] = t2;
  __syncthreads();
  float tot = red2[0] + red2[1] + red2[2] + red2[3];
  attn[((size_t)b * 256 + c) * 256 + d] = e / tot;
}

// ---- M = W_proj @ attn (fp32 vector GEMM, 256x256 per batch), M bf16 -------
__global__ __launch_bounds__(256) void k_mproj(const float* __restrict__ wproj,
                                               const float* __restrict__ attn,
                                               char* __restrict__ mb) {
  __shared__ float wt[32 * 256];
  __shared__ float at[32 * 256];
  const int t = threadIdx.x;
  const int o0 = blockIdx.x * 32, b = blockIdx.y;
#pragma unroll
  for (int i = 0; i < 32; ++i) wt[i * 256 + t] = wproj[(size_t)(o0 + i) * 256 + t];
  float acc[32];
#pragma unroll
  for (int o = 0; o < 32; ++o) acc[o] = 0.f;
  for (int ch = 0; ch < 8; ++ch) {
    __syncthreads();
#pragma unroll
    for (int j = 0; j < 32; ++j)
      at[j * 256 + t] = attn[((size_t)b * 256 + ch * 32 + j) * 256 + t];
    __syncthreads();
    for (int j = 0; j < 32; ++j) {
      float a = at[j * 256 + t];
#pragma unroll
      for (int o = 0; o < 32; ++o) acc[o] += wt[o * 256 + ch * 32 + j] * a;
    }
  }
  unsigned short* Mp = (unsigned short*)mb;
#pragma unroll
  for (int o = 0; o < 32; ++o)
    Mp[((size_t)b * 256 + o0 + o) * 256 + t] = f2bf(acc[o]);
}

// ---- GEMM3: out[b][o][n] = M[b] @ v  (B-operand = vT rows) -----------------
__global__ __launch_bounds__(256) void k_gemm3(const char* __restrict__ mb,
                                               const char* __restrict__ vt,
                                               float* __restrict__ out) {
  __shared__ char smem[32768];
  const int tid = threadIdx.x;
  const int nt = blockIdx.x, mt = blockIdx.y, b = blockIdx.z;
  f32x4 acc[4][4];
#pragma unroll
  for (int m = 0; m < 4; ++m)
#pragma unroll
    for (int nq = 0; nq < 4; ++nq) acc[m][nq] = (f32x4){0.f, 0.f, 0.f, 0.f};
  const char* Ap = mb + (size_t)(b * 256 + mt * 128) * 512;
  const char* Bp = vt + ((size_t)b * NN + (size_t)nt * 128) * 512;
  gemm_core(Ap, 512, Bp, 512, 4, smem, tid, acc);
  const int w = tid >> 6, l = tid & 63, wm = w >> 1, wn = w & 1;
#pragma unroll
  for (int m = 0; m < 4; ++m)
#pragma unroll
    for (int nq = 0; nq < 4; ++nq)
#pragma unroll
      for (int r = 0; r < 4; ++r) {
        int o = mt * 128 + wm * 64 + m * 16 + ((l >> 4) << 2) + r;
        int nn = nt * 128 + wn * 64 + nq * 16 + (l & 15);
        out[((size_t)b * 256 + o) * NN + nn] = acc[m][nq][r];
      }
}

extern "C" void kernel_launch(void* const* d_in, const int* in_sizes, int n_in,
                              void* d_out, int out_size, void* d_ws, size_t ws_size,
                              hipStream_t stream) {
  const float* x     = (const float*)d_in[0];
  const float* wqkv  = (const float*)d_in[1];
  const float* wdwf  = (const float*)d_in[2];
  const float* temp  = (const float*)d_in[3];
  const float* wproj = (const float*)d_in[4];
  float* out = (float*)d_out;
  char* ws = (char*)d_ws;

  // Workspace layout (bytes). xT region is dead after k_gemm1, so it's
  // unioned with the post-GEMM1 buffers (spart/attn/M/inv).
  char*  xt    = ws;                          // bf16 [B][N][C]      67,108,864
  float* spart = (float*)ws;                  // f32 [KS][B][256][256] 16,777,216
  float* attn  = (float*)(ws + 16777216);     // f32 [B][256][256]    2,097,152
  char*  mb    = ws + 18874368;               // bf16 [B][256][256]   1,048,576
  float* inv   = (float*)(ws + 19922944);     // f32 [B][512]            16,384
  char*  wdw   = ws + 67108864;               // bf16 [768][256]        393,216
  char*  qk    = ws + 67502080;               // bf16 [B][512][N]   134,217,728
  char*  vt    = ws + 201719808;              // bf16 [B][N][256]    67,108,864
  // total: 268,828,672 bytes

  k_prepw<<<dim3(768), dim3(256), 0, stream>>>(wqkv, wdwf, wdw);
  k_transpose<<<dim3(256, 4, 8), dim3(256), 0, stream>>>(x, xt);
  k_gemm1<<<dim3(128, 6, 8), dim3(256), 0, stream>>>(wdw, xt, qk, vt);
  k_norm<<<dim3(1024), dim3(256), 0, stream>>>(qk, inv);
  k_gemm2<<<dim3(4, 8, 8), dim3(256), 0, stream>>>(qk, spart);
  k_softmax<<<dim3(256, 8), dim3(256), 0, stream>>>(spart, inv, temp, attn);
  k_mproj<<<dim3(8, 8), dim3(256), 0, stream>>>(wproj, attn, mb);
  k_gemm3<<<dim3(128, 2, 8), dim3(256), 0, stream>>>(mb, vt, out);
}